// Round 3
// baseline (226.846 us; speedup 1.0000x reference)
//
#include <hip/hip_runtime.h>

#define TOKENS 16384
#define KDIM   2048
#define NEXP   64
#define TOPK   6
#define BM     128
#define BK     32
#define XS     130   // 130%32=2 -> 2-way write conflicts (free); b64-aligned reads

// Kernel 1: LDS-tiled partial GEMM, register-prefetch double buffer.
// Block 256 -> 128 tokens x 64 experts; grid (128 tiles, ns splits).
// Thread: 8 tok x 4 exp = 32 FMA/k (64 VALU cyc) vs 4xb64+1xb128 LDS (~36 cyc).
__global__ __launch_bounds__(256, 4)
void moe_gemm_tile(const float* __restrict__ x, const float* __restrict__ wg,
                   float* __restrict__ part, int Kc) {
  __shared__ float xs[BK * XS];     // transposed: xs[k][tok]
  __shared__ float ws[BK * NEXP];   // ws[k][expert]

  const int t    = threadIdx.x;
  const int row0 = blockIdx.x * BM;
  const int k0   = blockIdx.y * Kc;

  const int eg = t & 15;   // experts eg*4..+3
  const int tg = t >> 4;   // tokens  tg*8..+7

  const int lrow = t >> 3; // staging row (0..31)
  const int c4   = t & 7;  // staging float4 column

  float acc[8][4];
#pragma unroll
  for (int i = 0; i < 8; ++i)
#pragma unroll
    for (int j = 0; j < 4; ++j) acc[i][j] = 0.f;

  const float* xg = x + (size_t)row0 * KDIM + k0 + c4 * 4;
  float4 px[4], pw[2];

#define PREFETCH(KK)                                                         \
  {                                                                          \
    _Pragma("unroll")                                                        \
    for (int r = 0; r < 4; ++r)                                              \
      px[r] = *(const float4*)(xg + (size_t)(lrow + r * 32) * KDIM + (KK));  \
    const float* wp = wg + (size_t)(k0 + (KK)) * NEXP + t * 8;               \
    pw[0] = *(const float4*)(wp);                                            \
    pw[1] = *(const float4*)(wp + 4);                                        \
  }

  PREFETCH(0)

  for (int kk = 0; kk < Kc; kk += BK) {
    // regs -> LDS (xs transposed; 2-way bank aliasing only)
#pragma unroll
    for (int r = 0; r < 4; ++r) {
      const int row = lrow + r * 32;
      xs[(c4 * 4 + 0) * XS + row] = px[r].x;
      xs[(c4 * 4 + 1) * XS + row] = px[r].y;
      xs[(c4 * 4 + 2) * XS + row] = px[r].z;
      xs[(c4 * 4 + 3) * XS + row] = px[r].w;
    }
    *(float4*)(ws + t * 8)     = pw[0];
    *(float4*)(ws + t * 8 + 4) = pw[1];
    __syncthreads();

    if (kk + BK < Kc) PREFETCH(kk + BK)   // overlaps compute below

#pragma unroll 4
    for (int k = 0; k < BK; ++k) {
      const float2* xr = (const float2*)(xs + k * XS + tg * 8);
      const float2 a0 = xr[0], a1 = xr[1], a2 = xr[2], a3 = xr[3];
      const float4 w0 = *(const float4*)(ws + k * NEXP + eg * 4);
      const float xv[8] = {a0.x, a0.y, a1.x, a1.y, a2.x, a2.y, a3.x, a3.y};
#pragma unroll
      for (int i = 0; i < 8; ++i) {
        acc[i][0] += xv[i] * w0.x;
        acc[i][1] += xv[i] * w0.y;
        acc[i][2] += xv[i] * w0.z;
        acc[i][3] += xv[i] * w0.w;
      }
    }
    __syncthreads();
  }

  // part[ks][token][expert]
  float* pp = part + ((size_t)blockIdx.y * TOKENS + row0 + tg * 8) * NEXP + eg * 4;
#pragma unroll
  for (int i = 0; i < 8; ++i)
    *(float4*)(pp + (size_t)i * NEXP) =
        make_float4(acc[i][0], acc[i][1], acc[i][2], acc[i][3]);
}

// Kernel 2: 16 lanes per token, 4 experts/lane. Sum ns partials, softmax,
// 6 argmax rounds with jax tie-break (equal -> lower index).
// out: indices (as float) then scores.
__global__ __launch_bounds__(256)
void moe_softmax_topk(const float* __restrict__ part, float* __restrict__ out, int ns) {
  const int lane = threadIdx.x & 63;
  const int wid  = threadIdx.x >> 6;
  const int sub  = lane & 15;
  const int tok  = blockIdx.x * 16 + wid * 4 + (lane >> 4);

  float v[4] = {0.f, 0.f, 0.f, 0.f};
  for (int ks = 0; ks < ns; ++ks) {
    const float4 p = *(const float4*)(part + ((size_t)ks * TOKENS + tok) * NEXP + sub * 4);
    v[0] += p.x; v[1] += p.y; v[2] += p.z; v[3] += p.w;
  }

  float m = fmaxf(fmaxf(v[0], v[1]), fmaxf(v[2], v[3]));
#pragma unroll
  for (int off = 1; off < 16; off <<= 1) m = fmaxf(m, __shfl_xor(m, off));
  float p0 = expf(v[0] - m), p1 = expf(v[1] - m), p2 = expf(v[2] - m), p3 = expf(v[3] - m);
  float s = p0 + p1 + p2 + p3;
#pragma unroll
  for (int off = 1; off < 16; off <<= 1) s += __shfl_xor(s, off);
  v[0] = p0 / s; v[1] = p1 / s; v[2] = p2 / s; v[3] = p3 / s;

  float resv = 0.f; int resi = 0;
#pragma unroll
  for (int r = 0; r < TOPK; ++r) {
    float bv = v[0]; int bi = sub * 4;
#pragma unroll
    for (int j = 1; j < 4; ++j)
      if (v[j] > bv) { bv = v[j]; bi = sub * 4 + j; }
#pragma unroll
    for (int off = 1; off < 16; off <<= 1) {
      const float ov = __shfl_xor(bv, off);
      const int   oi = __shfl_xor(bi, off);
      if (ov > bv || (ov == bv && oi < bi)) { bv = ov; bi = oi; }
    }
    if (sub == r) { resv = bv; resi = bi; }
    if ((bi >> 2) == sub) v[bi & 3] = -1.f;
  }

  if (sub < TOPK) {
    out[(size_t)tok * TOPK + sub] = (float)resi;
    out[(size_t)TOKENS * TOPK + (size_t)tok * TOPK + sub] = resv;
  }
}

extern "C" void kernel_launch(void* const* d_in, const int* in_sizes, int n_in,
                              void* d_out, int out_size, void* d_ws, size_t ws_size,
                              hipStream_t stream) {
  const float* x  = (const float*)d_in[0];
  const float* wg = (const float*)d_in[1];
  float* out  = (float*)d_out;
  float* part = (float*)d_ws;

  int ns = 8;
  while (ns > 1 && (size_t)ns * TOKENS * NEXP * sizeof(float) > ws_size) ns >>= 1;
  const int Kc = KDIM / ns;

  dim3 g1(TOKENS / BM, ns);
  moe_gemm_tile<<<g1, dim3(256), 0, stream>>>(x, wg, part, Kc);
  moe_softmax_topk<<<dim3(TOKENS / 16), dim3(256), 0, stream>>>(part, out, ns);
}

// Round 4
// 226.197 us; speedup vs baseline: 1.0029x; 1.0029x over previous
//
#include <hip/hip_runtime.h>

#define TOKENS 16384
#define KDIM   2048
#define NEXP   64
#define TOPK   6
#define BM     128
#define BK     32
#define XS     130   // 130%32=2 -> 2-way bank aliasing (free); b64-aligned reads

// Kernel 1: LDS-tiled partial GEMM. Block 256 = 2 K-halves x (16 tg x 8 eg).
// Per thread: 8 tok x 8 exp = 64 acc; per k: 64B LDS -> 64 FMA (VALU-bound).
// Waves 0-1 compute k in [0,16) of each BK tile, waves 2-3 k in [16,32);
// halves are summed through LDS at the end.
__global__ __launch_bounds__(256, 4)
void moe_gemm_tile(const float* __restrict__ x, const float* __restrict__ wg,
                   float* __restrict__ part, int Kc) {
  __shared__ float smem[8192];           // 32 KB: staging (24.3 KB) then reduction (32 KB)
  float* xs = smem;                      // [BK][XS] transposed x
  float* ws = smem + BK * XS;            // [BK][NEXP]

  const int t    = threadIdx.x;
  const int row0 = blockIdx.x * BM;
  const int k0   = blockIdx.y * Kc;

  const int kh  = t >> 7;        // K-half (0: waves 0-1, 1: waves 2-3)
  const int tid = t & 127;
  const int tg  = tid >> 3;      // tokens tg*8..+7  (0..15)
  const int eg  = tid & 7;       // experts eg*8..+7 (0..7)

  const int lrow = t >> 3;       // staging row 0..31
  const int c4   = t & 7;        // staging float4 k-col

  float acc[8][8];
#pragma unroll
  for (int i = 0; i < 8; ++i)
#pragma unroll
    for (int j = 0; j < 8; ++j) acc[i][j] = 0.f;

  const float* xg = x + (size_t)row0 * KDIM + k0 + c4 * 4;
  float4 px[4], pw[2];

#define PREFETCH(KK)                                                         \
  {                                                                          \
    _Pragma("unroll")                                                        \
    for (int r = 0; r < 4; ++r)                                              \
      px[r] = *(const float4*)(xg + (size_t)(lrow + r * 32) * KDIM + (KK));  \
    const float* wp = wg + (size_t)(k0 + (KK)) * NEXP + t * 8;               \
    pw[0] = *(const float4*)(wp);                                            \
    pw[1] = *(const float4*)(wp + 4);                                        \
  }

  PREFETCH(0)

  for (int kk = 0; kk < Kc; kk += BK) {
#pragma unroll
    for (int r = 0; r < 4; ++r) {
      const int row = lrow + r * 32;
      xs[(c4 * 4 + 0) * XS + row] = px[r].x;
      xs[(c4 * 4 + 1) * XS + row] = px[r].y;
      xs[(c4 * 4 + 2) * XS + row] = px[r].z;
      xs[(c4 * 4 + 3) * XS + row] = px[r].w;
    }
    *(float4*)(ws + t * 8)     = pw[0];
    *(float4*)(ws + t * 8 + 4) = pw[1];
    __syncthreads();

    if (kk + BK < Kc) PREFETCH(kk + BK)   // overlaps compute below

    const int kb = kh * (BK / 2);
#pragma unroll 4
    for (int ki = 0; ki < BK / 2; ++ki) {
      const int k = kb + ki;
      const float2* xr = (const float2*)(xs + k * XS + tg * 8);
      const float2 a0 = xr[0], a1 = xr[1], a2 = xr[2], a3 = xr[3];
      const float4 w0 = *(const float4*)(ws + k * NEXP + eg * 8);
      const float4 w1 = *(const float4*)(ws + k * NEXP + eg * 8 + 4);
      const float xv[8] = {a0.x, a0.y, a1.x, a1.y, a2.x, a2.y, a3.x, a3.y};
#pragma unroll
      for (int i = 0; i < 8; ++i) {
        acc[i][0] += xv[i] * w0.x;  acc[i][1] += xv[i] * w0.y;
        acc[i][2] += xv[i] * w0.z;  acc[i][3] += xv[i] * w0.w;
        acc[i][4] += xv[i] * w1.x;  acc[i][5] += xv[i] * w1.y;
        acc[i][6] += xv[i] * w1.z;  acc[i][7] += xv[i] * w1.w;
      }
    }
    __syncthreads();
  }

  // combine K-halves: kh=1 -> LDS (strided, 2-way banks = free), kh=0 adds.
  if (kh == 1) {
#pragma unroll
    for (int i = 0; i < 8; ++i)
#pragma unroll
      for (int j = 0; j < 8; ++j)
        smem[(i * 8 + j) * 128 + tid] = acc[i][j];
  }
  __syncthreads();
  if (kh == 0) {
#pragma unroll
    for (int i = 0; i < 8; ++i)
#pragma unroll
      for (int j = 0; j < 8; ++j)
        acc[i][j] += smem[(i * 8 + j) * 128 + tid];

    float* pp = part + ((size_t)blockIdx.y * TOKENS + row0 + tg * 8) * NEXP + eg * 8;
#pragma unroll
    for (int i = 0; i < 8; ++i) {
      *(float4*)(pp + (size_t)i * NEXP) =
          make_float4(acc[i][0], acc[i][1], acc[i][2], acc[i][3]);
      *(float4*)(pp + (size_t)i * NEXP + 4) =
          make_float4(acc[i][4], acc[i][5], acc[i][6], acc[i][7]);
    }
  }
}

// Kernel 2: 16 lanes per token, 4 experts/lane. Sum ns partials, softmax,
// 6 argmax rounds with jax tie-break (equal -> lower index).
// out: indices (as float) then scores.
__global__ __launch_bounds__(256)
void moe_softmax_topk(const float* __restrict__ part, float* __restrict__ out, int ns) {
  const int lane = threadIdx.x & 63;
  const int wid  = threadIdx.x >> 6;
  const int sub  = lane & 15;
  const int tok  = blockIdx.x * 16 + wid * 4 + (lane >> 4);

  float v[4] = {0.f, 0.f, 0.f, 0.f};
  for (int ks = 0; ks < ns; ++ks) {
    const float4 p = *(const float4*)(part + ((size_t)ks * TOKENS + tok) * NEXP + sub * 4);
    v[0] += p.x; v[1] += p.y; v[2] += p.z; v[3] += p.w;
  }

  float m = fmaxf(fmaxf(v[0], v[1]), fmaxf(v[2], v[3]));
#pragma unroll
  for (int off = 1; off < 16; off <<= 1) m = fmaxf(m, __shfl_xor(m, off));
  float p0 = expf(v[0] - m), p1 = expf(v[1] - m), p2 = expf(v[2] - m), p3 = expf(v[3] - m);
  float s = p0 + p1 + p2 + p3;
#pragma unroll
  for (int off = 1; off < 16; off <<= 1) s += __shfl_xor(s, off);
  v[0] = p0 / s; v[1] = p1 / s; v[2] = p2 / s; v[3] = p3 / s;

  float resv = 0.f; int resi = 0;
#pragma unroll
  for (int r = 0; r < TOPK; ++r) {
    float bv = v[0]; int bi = sub * 4;
#pragma unroll
    for (int j = 1; j < 4; ++j)
      if (v[j] > bv) { bv = v[j]; bi = sub * 4 + j; }
#pragma unroll
    for (int off = 1; off < 16; off <<= 1) {
      const float ov = __shfl_xor(bv, off);
      const int   oi = __shfl_xor(bi, off);
      if (ov > bv || (ov == bv && oi < bi)) { bv = ov; bi = oi; }
    }
    if (sub == r) { resv = bv; resi = bi; }
    if ((bi >> 2) == sub) v[bi & 3] = -1.f;
  }

  if (sub < TOPK) {
    out[(size_t)tok * TOPK + sub] = (float)resi;
    out[(size_t)TOKENS * TOPK + (size_t)tok * TOPK + sub] = resv;
  }
}

extern "C" void kernel_launch(void* const* d_in, const int* in_sizes, int n_in,
                              void* d_out, int out_size, void* d_ws, size_t ws_size,
                              hipStream_t stream) {
  const float* x  = (const float*)d_in[0];
  const float* wg = (const float*)d_in[1];
  float* out  = (float*)d_out;
  float* part = (float*)d_ws;

  int ns = 8;
  while (ns > 1 && (size_t)ns * TOKENS * NEXP * sizeof(float) > ws_size) ns >>= 1;
  const int Kc = KDIM / ns;

  dim3 g1(TOKENS / BM, ns);
  moe_gemm_tile<<<g1, dim3(256), 0, stream>>>(x, wg, part, Kc);
  moe_softmax_topk<<<dim3(TOKENS / 16), dim3(256), 0, stream>>>(part, out, ns);
}